// Round 9
// baseline (218.686 us; speedup 1.0000x reference)
//
#include <hip/hip_runtime.h>
#include <hip/hip_fp16.h>

#define IMG_W 2048
#define IMG_H 2048
#define HALF  10          // max_coc // 2
#define TILE  64          // 64x64 output tile
#define LW 84             // halo dim (64 + 2*10)
#define NSTG (LW * LW)    // 7056 staged pixels

// LUT plane per k, stride 78 dwords (312 B, even -> b64-aligned; k*312 fits u16):
//   dwords  0..47 : wy quads; entry aa (0..23) = 2 dwords:
//                   d0 = pack(wy(aa-10), wy(aa-11))  [rows r0,r1]
//                   d1 = pack(wy(aa-12), wy(aa-13))  [rows r2,r3]
//   dwords 48..61 : wx pairs   h: pack(wx(2h-13), wx(2h-12))   (pos 2h,2h+1)
//   dwords 62..75 : wx shifted j: pack(wx(2j-12), wx(2j-11))   (pos 2j+1,2j+2)
//   dwords 76..77 : pad
#define L_KSD 78
#define L_KSB 312
#define L_NDW (22 * L_KSD)     // 1716 dwords = 6864 B

__device__ __forceinline__ __half2 h2(uint u)  { union { uint a; __half2 b; } c; c.a = u; return c.b; }
__device__ __forceinline__ uint pack2(float a, float b) {
    return (uint)__half_as_ushort(__float2half(a)) |
           ((uint)__half_as_ushort(__float2half(b)) << 16);
}
// weight factors: w(k,oy,ox) = wyv(k,oy) * wxv(k,ox); norm folded into wy
__device__ __forceinline__ float wyv(int k, int oy) {
    int a = abs(oy), hk = k >> 1;
    if (a > hk) return 0.f;
    if (k <= 1) return 1.f;
    float kk = (float)(k * k);
    return expf(-(float)(oy * oy) * 18.f / kk) * 5.7295780f / kk;
}
__device__ __forceinline__ float wxv(int k, int ox) {
    int a = abs(ox), hk = k >> 1;
    if (a > hk) return 0.f;
    if (k <= 1) return 1.f;
    float kk = (float)(k * k);
    return expf(-(float)(ox * ox) * 18.f / kk);
}

// VOP3P with explicit op_sel broadcasts (zero splat instructions):
#define FMA_LO(acc, px, w) \
    asm("v_pk_fma_f16 %0, %1, %2, %0 op_sel:[0,0,0] op_sel_hi:[0,1,1]" \
        : "+v"(acc) : "v"(px), "v"(w))
#define FMA_HI(acc, px, w) \
    asm("v_pk_fma_f16 %0, %1, %2, %0 op_sel:[1,0,0] op_sel_hi:[1,1,1]" \
        : "+v"(acc) : "v"(px), "v"(w))
#define MUL_WYLO(d, wx2, wy2) \
    asm("v_pk_mul_f16 %0, %1, %2 op_sel:[0,0] op_sel_hi:[1,0]" \
        : "=v"(d) : "v"(wx2), "v"(wy2))
#define MUL_WYHI(d, wx2, wy2) \
    asm("v_pk_mul_f16 %0, %1, %2 op_sel:[0,1] op_sel_hi:[1,1]" \
        : "=v"(d) : "v"(wx2), "v"(wy2))

__global__ __launch_bounds__(256, 2)
void defocus_4x4_kernel(const float* __restrict__ img,
                        const int* __restrict__ ks,
                        float* __restrict__ out)
{
    __shared__ __align__(16) uint  lutw[L_NDW];   // 6864 B (LDS offset 0)
    __shared__ __align__(16) uint2 tile[NSTG];    // 56448 B; phase-major cols

    const int tid = threadIdx.x;
    const int X0 = blockIdx.x * TILE;
    const int Y0 = blockIdx.y * TILE;

    // ---- build LUT ----
    for (int i = tid; i < L_NDW; i += 256) {
        int k = i / L_KSD;
        int d = i - k * L_KSD;
        float lo = 0.f, hi = 0.f;
        if (d < 48) {                        // wy quad: entry aa, half q
            int aa = d >> 1, q = d & 1;
            lo = wyv(k, aa - 10 - 2 * q);
            hi = wyv(k, aa - 11 - 2 * q);
        } else if (d < 62) {                 // wx pair, pos (2h, 2h+1)
            int hh = d - 48;
            lo = wxv(k, 2 * hh - 13);
            hi = wxv(k, 2 * hh - 12);
        } else if (d < 76) {                 // shifted wx pair, pos (2j+1, 2j+2)
            int j = d - 62;
            lo = wxv(k, 2 * j - 12);
            hi = wxv(k, 2 * j - 11);
        }
        lutw[i] = pack2(lo, hi);
    }

    // ---- stage 84x84 halo tile, phase-major: {f16 r|g , u16 koffB=k*312 | f16 b} ----
    for (int i = tid; i < NSTG; i += 256) {
        int r = i / LW;
        int c = i - r * LW;
        int gy = Y0 - HALF + r;
        int gx = X0 - HALF + c;
        float fr = 0.f, fg = 0.f, fb = 0.f;
        uint koffB = 0;
        if (gy >= 0 && gy < IMG_H && gx >= 0 && gx < IMG_W) {
            int p = gy * IMG_W + gx;
            fr = img[p * 3 + 0];
            fg = img[p * 3 + 1];
            fb = img[p * 3 + 2];
            koffB = (uint)(ks[p] * L_KSB);
        }
        uint2 v;
        v.x = pack2(fr, fg);
        v.y = koffB | ((uint)__half_as_ushort(__float2half(fb)) << 16);
        tile[r * LW + (c & 3) * 21 + (c >> 2)] = v;
    }
    __syncthreads();

    const int tx = tid & 15;
    const int ty = tid >> 4;
    const int colbase = tx * 4;
    const int rowbase = ty * 4;
    const int pxbase  = rowbase * LW + tx;   // per-iter tile reads: pxbase + IMM-ish

    // f16 pair accumulators: A32[r][ch]=(col3,col2), A10[r][ch]=(col1,col0)
    uint A32[4][3] = {}, A10[4][3] = {};
    float mc[4][4][3];                       // f32 masters [r][col][ch]
    #pragma unroll
    for (int r = 0; r < 4; ++r)
        #pragma unroll
        for (int c = 0; c < 3; ++c)
            mc[r][0][c] = mc[r][1][c] = mc[r][2][c] = mc[r][3][c] = 0.f;

#define ROW(aa)                                                                    \
    { const int pxrow = pxbase + (aa) * LW;                                        \
      _Pragma("unroll")                                                            \
      for (int b = 0; b < 24; ++b) {                                               \
          uint2 p = tile[pxrow + (b & 3) * 21 + (b >> 2)];                         \
          const char* wp = (const char*)lutw + (p.y & 0xffffu);                    \
          uint2 wy = *(const uint2*)(wp + 8 * (aa));                               \
          const uint* wpu = (const uint*)wp;                                       \
          uint w32, w10;  /* wx: (pos b,b+1)=(col3,col2), (pos b+2,b+3)=(col1,col0) */ \
          if ((b & 1) == 0) {                                                      \
              w32 = wpu[48 + (b >> 1)];                                            \
              w10 = wpu[49 + (b >> 1)];                                            \
          } else {                                                                 \
              w32 = wpu[62 + ((b - 1) >> 1)];                                      \
              w10 = wpu[63 + ((b - 1) >> 1)];                                      \
          }                                                                        \
          uint W32[4], W10[4];                                                     \
          MUL_WYLO(W32[0], w32, wy.x); MUL_WYHI(W32[1], w32, wy.x);                \
          MUL_WYLO(W32[2], w32, wy.y); MUL_WYHI(W32[3], w32, wy.y);                \
          MUL_WYLO(W10[0], w10, wy.x); MUL_WYHI(W10[1], w10, wy.x);                \
          MUL_WYLO(W10[2], w10, wy.y); MUL_WYHI(W10[3], w10, wy.y);                \
          _Pragma("unroll")                                                        \
          for (int r = 0; r < 4; ++r) {                                            \
              FMA_LO(A32[r][0], p.x, W32[r]);                                      \
              FMA_HI(A32[r][1], p.x, W32[r]);                                      \
              FMA_HI(A32[r][2], p.y, W32[r]);                                      \
              FMA_LO(A10[r][0], p.x, W10[r]);                                      \
              FMA_HI(A10[r][1], p.x, W10[r]);                                      \
              FMA_HI(A10[r][2], p.y, W10[r]);                                      \
          }                                                                        \
      } }

#define FLUSH()                                                        \
    { _Pragma("unroll")                                                \
      for (int r = 0; r < 4; ++r) {                                    \
          _Pragma("unroll")                                            \
          for (int c = 0; c < 3; ++c) {                                \
              float2 f3 = __half22float2(h2(A32[r][c]));               \
              float2 f1 = __half22float2(h2(A10[r][c]));               \
              mc[r][3][c] += f3.x; mc[r][2][c] += f3.y;                \
              mc[r][1][c] += f1.x; mc[r][0][c] += f1.y;                \
              A32[r][c] = 0; A10[r][c] = 0;                            \
          }                                                            \
      } }

    // 24 source rows, flush f16 partials (<=48 taps) every 2 rows
    #pragma unroll 1
    for (int ap = 0; ap < 12; ++ap) {
        ROW(2 * ap);
        ROW(2 * ap + 1);
        FLUSH();
    }

    // ---- store ----
    #pragma unroll
    for (int r = 0; r < 4; ++r) {
        int gy = Y0 + rowbase + r;
        #pragma unroll
        for (int m = 0; m < 4; ++m) {
            int gx = X0 + colbase + m;
            int o = (gy * IMG_W + gx) * 3;
            out[o + 0] = mc[r][m][0];
            out[o + 1] = mc[r][m][1];
            out[o + 2] = mc[r][m][2];
        }
    }
#undef ROW
#undef FLUSH
}

extern "C" void kernel_launch(void* const* d_in, const int* in_sizes, int n_in,
                              void* d_out, int out_size, void* d_ws, size_t ws_size,
                              hipStream_t stream) {
    const float* img = (const float*)d_in[0];
    const int*   ks  = (const int*)d_in[1];
    float* out = (float*)d_out;

    dim3 grid(IMG_W / TILE, IMG_H / TILE);   // 32 x 32
    dim3 block(256);
    defocus_4x4_kernel<<<grid, block, 0, stream>>>(img, ks, out);
}

// Round 10
// 185.230 us; speedup vs baseline: 1.1806x; 1.1806x over previous
//
#include <hip/hip_runtime.h>
#include <hip/hip_fp16.h>

#define IMG_W 2048
#define IMG_H 2048
#define HALF  10          // max_coc // 2
#define TILE  64          // 64x64 output tile
#define LW 84             // halo dim
#define NSTG (LW * LW)    // 7056

// Separable LUT, one 51-dword plane per k (ODD stride -> per-lane-k bank-spread):
//   dwords  0..21 : wy pairs; entry a = pack2(wy(a-10), wy(a-11))  (lo->r0, hi->r1)
//   dwords 22..35 : wx pairs;  22+h = pack2(wx(2h-13), wx(2h-12))   (pos 2h,2h+1)
//   dwords 36..49 : wx shifted; 36+j = pack2(wx(2j-12), wx(2j-11))  (pos 2j+1,2j+2)
//   dword  50     : pad
#define L_KSD 51
#define L_KSB 204              // byte plane stride (k*204 fits u16)
#define L_NDW (22 * L_KSD)     // 1122 dwords = 4488 B

__device__ __forceinline__ __half2 h2(uint u)  { union { uint a; __half2 b; } c; c.a = u; return c.b; }
__device__ __forceinline__ uint pack2(float a, float b) {
    return (uint)__half_as_ushort(__float2half(a)) |
           ((uint)__half_as_ushort(__float2half(b)) << 16);
}
// weight factors: w(k,oy,ox) = wyv(k,oy) * wxv(k,ox); norm folded into wy
__device__ __forceinline__ float wyv(int k, int oy) {
    int a = abs(oy), hk = k >> 1;
    if (a > hk) return 0.f;
    if (k <= 1) return 1.f;
    float kk = (float)(k * k);
    return expf(-(float)(oy * oy) * 18.f / kk) * 5.7295780f / kk;
}
__device__ __forceinline__ float wxv(int k, int ox) {
    int a = abs(ox), hk = k >> 1;
    if (a > hk) return 0.f;
    if (k <= 1) return 1.f;
    float kk = (float)(k * k);
    return expf(-(float)(ox * ox) * 18.f / kk);
}

// VOP3P with explicit op_sel broadcasts (zero splat instructions):
#define FMA_LO(acc, px, w) \
    asm("v_pk_fma_f16 %0, %1, %2, %0 op_sel:[0,0,0] op_sel_hi:[0,1,1]" \
        : "+v"(acc) : "v"(px), "v"(w))
#define FMA_HI(acc, px, w) \
    asm("v_pk_fma_f16 %0, %1, %2, %0 op_sel:[1,0,0] op_sel_hi:[1,1,1]" \
        : "+v"(acc) : "v"(px), "v"(w))
#define MUL_WYLO(d, wx2, wy2) \
    asm("v_pk_mul_f16 %0, %1, %2 op_sel:[0,0] op_sel_hi:[1,0]" \
        : "=v"(d) : "v"(wx2), "v"(wy2))
#define MUL_WYHI(d, wx2, wy2) \
    asm("v_pk_mul_f16 %0, %1, %2 op_sel:[0,1] op_sel_hi:[1,1]" \
        : "=v"(d) : "v"(wx2), "v"(wy2))

__global__ __launch_bounds__(512, 4)
void defocus_512_kernel(const float* __restrict__ img,
                        const int* __restrict__ ks,
                        float* __restrict__ out)
{
    __shared__ uint  lutw[L_NDW + 2];   // 4496 B  (LDS offset 0)
    __shared__ uint2 tile[NSTG];        // 56448 B; phase-major cols

    const int tid = threadIdx.x;
    const int X0 = blockIdx.x * TILE;
    const int Y0 = blockIdx.y * TILE;

    // ---- build separable LUT ----
    for (int i = tid; i < L_NDW; i += 512) {
        int k = i / L_KSD;
        int d = i - k * L_KSD;
        float lo = 0.f, hi = 0.f;
        if (d < 22) {                       // wy pair for source row a=d
            lo = wyv(k, d - 10);
            hi = wyv(k, d - 11);
        } else if (d < 36) {                // wx pair, pos (2h, 2h+1)
            int j = d - 22;
            lo = wxv(k, 2 * j - 13);
            hi = wxv(k, 2 * j - 12);
        } else if (d < 50) {                // shifted wx pair, pos (2j+1, 2j+2)
            int j = d - 36;
            lo = wxv(k, 2 * j - 12);
            hi = wxv(k, 2 * j - 11);
        }
        lutw[i] = pack2(lo, hi);
    }

    // ---- stage 84x84 halo tile, phase-major: {f16 r|g , u16 koffB=k*204 | f16 b} ----
    for (int i = tid; i < NSTG; i += 512) {
        int r = i / LW;
        int c = i - r * LW;
        int gy = Y0 - HALF + r;
        int gx = X0 - HALF + c;
        float fr = 0.f, fg = 0.f, fb = 0.f;
        uint koffB = 0;
        if (gy >= 0 && gy < IMG_H && gx >= 0 && gx < IMG_W) {
            int p = gy * IMG_W + gx;
            fr = img[p * 3 + 0];
            fg = img[p * 3 + 1];
            fb = img[p * 3 + 2];
            koffB = (uint)(ks[p] * L_KSB);
        }
        uint2 v;
        v.x = pack2(fr, fg);
        v.y = koffB | ((uint)__half_as_ushort(__float2half(fb)) << 16);
        tile[r * LW + (c & 3) * 21 + (c >> 2)] = v;
    }
    __syncthreads();

    const int tx = tid & 15;       // 16 thread-cols
    const int ty = tid >> 4;       // 32 thread-rows
    const int colbase = tx * 4;
    const int rowbase = ty * 2;
    const int pxbase  = rowbase * LW + tx;   // per-iter tile reads: pxbase + IMM

    // f16 pair accumulators: A32[r][ch]=(col3,col2), A10[r][ch]=(col1,col0)
    uint A32[2][3] = {{0,0,0},{0,0,0}}, A10[2][3] = {{0,0,0},{0,0,0}};
    float mc[2][4][3];              // f32 masters [r][col][ch]
    #pragma unroll
    for (int r = 0; r < 2; ++r)
        #pragma unroll
        for (int c = 0; c < 3; ++c)
            mc[r][0][c] = mc[r][1][c] = mc[r][2][c] = mc[r][3][c] = 0.f;

#define ROW(aa)                                                                    \
    { _Pragma("unroll")                                                            \
      for (int b = 0; b < 24; ++b) {                                               \
          uint2 p = tile[pxbase + (aa) * LW + (b & 3) * 21 + (b >> 2)];            \
          const char* wp = (const char*)lutw + (p.y & 0xffffu);                    \
          uint wy2 = *(const uint*)(wp + 4 * (aa));                                \
          uint w32, w10;   /* wx pairs: (pos b,b+1)=(col3,col2), (pos b+2,b+3)=(col1,col0) */ \
          if ((b & 1) == 0) {                                                      \
              w32 = *(const uint*)(wp + 4 * (22 + (b >> 1)));                      \
              w10 = *(const uint*)(wp + 4 * (23 + (b >> 1)));                      \
          } else {                                                                 \
              w32 = *(const uint*)(wp + 4 * (36 + ((b - 1) >> 1)));                \
              w10 = *(const uint*)(wp + 4 * (36 + ((b + 1) >> 1)));                \
          }                                                                        \
          uint W320, W100, W321, W101;                                             \
          MUL_WYLO(W320, w32, wy2);                                                \
          MUL_WYLO(W100, w10, wy2);                                                \
          MUL_WYHI(W321, w32, wy2);                                                \
          MUL_WYHI(W101, w10, wy2);                                                \
          FMA_LO(A32[0][0], p.x, W320);                                            \
          FMA_HI(A32[0][1], p.x, W320);                                            \
          FMA_HI(A32[0][2], p.y, W320);                                            \
          FMA_LO(A10[0][0], p.x, W100);                                            \
          FMA_HI(A10[0][1], p.x, W100);                                            \
          FMA_HI(A10[0][2], p.y, W100);                                            \
          FMA_LO(A32[1][0], p.x, W321);                                            \
          FMA_HI(A32[1][1], p.x, W321);                                            \
          FMA_HI(A32[1][2], p.y, W321);                                            \
          FMA_LO(A10[1][0], p.x, W101);                                            \
          FMA_HI(A10[1][1], p.x, W101);                                            \
          FMA_HI(A10[1][2], p.y, W101);                                            \
      } }

#define FLUSH()                                                        \
    { _Pragma("unroll")                                                \
      for (int r = 0; r < 2; ++r) {                                    \
          _Pragma("unroll")                                            \
          for (int c = 0; c < 3; ++c) {                                \
              float2 f3 = __half22float2(h2(A32[r][c]));               \
              float2 f1 = __half22float2(h2(A10[r][c]));               \
              mc[r][3][c] += f3.x; mc[r][2][c] += f3.y;                \
              mc[r][1][c] += f1.x; mc[r][0][c] += f1.y;                \
              A32[r][c] = 0; A10[r][c] = 0;                            \
          }                                                            \
      } }

    // 22 source rows, flush f16 partials (<=48 taps) every 2 rows
    #pragma unroll 1
    for (int ap = 0; ap < 11; ++ap) {
        ROW(2 * ap);
        ROW(2 * ap + 1);
        FLUSH();
    }

    // ---- store ----
    #pragma unroll
    for (int r = 0; r < 2; ++r) {
        int gy = Y0 + rowbase + r;
        #pragma unroll
        for (int m = 0; m < 4; ++m) {
            int gx = X0 + colbase + m;
            int o = (gy * IMG_W + gx) * 3;
            out[o + 0] = mc[r][m][0];
            out[o + 1] = mc[r][m][1];
            out[o + 2] = mc[r][m][2];
        }
    }
#undef ROW
#undef FLUSH
}

extern "C" void kernel_launch(void* const* d_in, const int* in_sizes, int n_in,
                              void* d_out, int out_size, void* d_ws, size_t ws_size,
                              hipStream_t stream) {
    const float* img = (const float*)d_in[0];
    const int*   ks  = (const int*)d_in[1];
    float* out = (float*)d_out;

    dim3 grid(IMG_W / TILE, IMG_H / TILE);   // 32 x 32
    dim3 block(512);
    defocus_512_kernel<<<grid, block, 0, stream>>>(img, ks, out);
}

// Round 11
// 176.844 us; speedup vs baseline: 1.2366x; 1.0474x over previous
//
#include <hip/hip_runtime.h>
#include <hip/hip_fp16.h>

#define IMG_W 2048
#define IMG_H 2048
#define HALF  10          // max_coc // 2
#define TILE  64          // 64x64 output tile
#define LW 84             // halo dim
#define NSTG (LW * LW)    // 7056

// Separable LUT, one 51-dword plane per k (ODD stride -> injective k->bank):
//   dwords  0..21 : wy pairs; entry a = pack2(wy(a-10), wy(a-11))  (lo->r0, hi->r1)
//   dwords 22..35 : wx pairs;  22+h = pack2(wx(2h-13), wx(2h-12))   (pos 2h,2h+1)
//   dwords 36..49 : wx shifted; 36+j = pack2(wx(2j-12), wx(2j-11))  (pos 2j+1,2j+2)
//   dword  50     : pad
#define L_KSD 51
#define L_KSB 204              // byte plane stride (k*204 fits u16)
#define L_NDW (22 * L_KSD)     // 1122 dwords = 4488 B

__device__ __forceinline__ __half2 h2(uint u)  { union { uint a; __half2 b; } c; c.a = u; return c.b; }
__device__ __forceinline__ uint pack2(float a, float b) {
    return (uint)__half_as_ushort(__float2half(a)) |
           ((uint)__half_as_ushort(__float2half(b)) << 16);
}
// weight factors: w(k,oy,ox) = wyv(k,oy) * wxv(k,ox); norm folded into wy
__device__ __forceinline__ float wyv(int k, int oy) {
    int a = abs(oy), hk = k >> 1;
    if (a > hk) return 0.f;
    if (k <= 1) return 1.f;
    float kk = (float)(k * k);
    return expf(-(float)(oy * oy) * 18.f / kk) * 5.7295780f / kk;
}
__device__ __forceinline__ float wxv(int k, int ox) {
    int a = abs(ox), hk = k >> 1;
    if (a > hk) return 0.f;
    if (k <= 1) return 1.f;
    float kk = (float)(k * k);
    return expf(-(float)(ox * ox) * 18.f / kk);
}

// VOP3P with explicit op_sel broadcasts (zero splat instructions):
#define FMA_LO(acc, px, w) \
    asm("v_pk_fma_f16 %0, %1, %2, %0 op_sel:[0,0,0] op_sel_hi:[0,1,1]" \
        : "+v"(acc) : "v"(px), "v"(w))
#define FMA_HI(acc, px, w) \
    asm("v_pk_fma_f16 %0, %1, %2, %0 op_sel:[1,0,0] op_sel_hi:[1,1,1]" \
        : "+v"(acc) : "v"(px), "v"(w))
#define MUL_WYLO(d, wx2, wy2) \
    asm("v_pk_mul_f16 %0, %1, %2 op_sel:[0,0] op_sel_hi:[1,0]" \
        : "=v"(d) : "v"(wx2), "v"(wy2))
#define MUL_WYHI(d, wx2, wy2) \
    asm("v_pk_mul_f16 %0, %1, %2 op_sel:[0,1] op_sel_hi:[1,1]" \
        : "=v"(d) : "v"(wx2), "v"(wy2))

__global__ __launch_bounds__(512, 4)
void defocus_pipe_kernel(const float* __restrict__ img,
                         const int* __restrict__ ks,
                         float* __restrict__ out)
{
    __shared__ uint  lutw[L_NDW + 2];   // 4496 B  (LDS offset 0)
    __shared__ uint2 tile[NSTG];        // 56448 B; phase-major cols

    const int tid = threadIdx.x;
    const int X0 = blockIdx.x * TILE;
    const int Y0 = blockIdx.y * TILE;

    // ---- build separable LUT ----
    for (int i = tid; i < L_NDW; i += 512) {
        int k = i / L_KSD;
        int d = i - k * L_KSD;
        float lo = 0.f, hi = 0.f;
        if (d < 22) {                       // wy pair for source row a=d
            lo = wyv(k, d - 10);
            hi = wyv(k, d - 11);
        } else if (d < 36) {                // wx pair, pos (2h, 2h+1)
            int j = d - 22;
            lo = wxv(k, 2 * j - 13);
            hi = wxv(k, 2 * j - 12);
        } else if (d < 50) {                // shifted wx pair, pos (2j+1, 2j+2)
            int j = d - 36;
            lo = wxv(k, 2 * j - 12);
            hi = wxv(k, 2 * j - 11);
        }
        lutw[i] = pack2(lo, hi);
    }

    // ---- stage 84x84 halo tile, phase-major: {f16 r|g , u16 koffB=k*204 | f16 b} ----
    for (int i = tid; i < NSTG; i += 512) {
        int r = i / LW;
        int c = i - r * LW;
        int gy = Y0 - HALF + r;
        int gx = X0 - HALF + c;
        float fr = 0.f, fg = 0.f, fb = 0.f;
        uint koffB = 0;
        if (gy >= 0 && gy < IMG_H && gx >= 0 && gx < IMG_W) {
            int p = gy * IMG_W + gx;
            fr = img[p * 3 + 0];
            fg = img[p * 3 + 1];
            fb = img[p * 3 + 2];
            koffB = (uint)(ks[p] * L_KSB);
        }
        uint2 v;
        v.x = pack2(fr, fg);
        v.y = koffB | ((uint)__half_as_ushort(__float2half(fb)) << 16);
        tile[r * LW + (c & 3) * 21 + (c >> 2)] = v;
    }
    __syncthreads();

    const int tx = tid & 15;       // 16 thread-cols
    const int ty = tid >> 4;       // 32 thread-rows
    const int colbase = tx * 4;
    const int rowbase = ty * 2;
    const int pxbase  = rowbase * LW + tx;

    // f16 pair accumulators: A32[r][ch]=(col3,col2), A10[r][ch]=(col1,col0)
    uint A32[2][3] = {{0,0,0},{0,0,0}}, A10[2][3] = {{0,0,0},{0,0,0}};
    float mc[2][4][3];              // f32 masters [r][col][ch]
    #pragma unroll
    for (int r = 0; r < 2; ++r)
        #pragma unroll
        for (int c = 0; c < 3; ++c)
            mc[r][0][c] = mc[r][1][c] = mc[r][2][c] = mc[r][3][c] = 0.f;

    // phase-major px index for tap b (compile-time)
#define PIDX(b) (((b) & 3) * 21 + ((b) >> 2))

    // prefetch 8 pixels (b64 each) into registers
#define PXG(buf, B0)                                   \
    { buf[0] = tile[pxrow + PIDX((B0) + 0)];           \
      buf[1] = tile[pxrow + PIDX((B0) + 1)];           \
      buf[2] = tile[pxrow + PIDX((B0) + 2)];           \
      buf[3] = tile[pxrow + PIDX((B0) + 3)];           \
      buf[4] = tile[pxrow + PIDX((B0) + 4)];           \
      buf[5] = tile[pxrow + PIDX((B0) + 5)];           \
      buf[6] = tile[pxrow + PIDX((B0) + 6)];           \
      buf[7] = tile[pxrow + PIDX((B0) + 7)]; }

    // weight fetch for one tap (3 dwords off one per-lane base)
#define WLD1(w, pvv, aa, b)                                                        \
    { const uint* wp = (const uint*)((const char*)lutw + ((pvv).y & 0xffffu));     \
      (w).x = wp[(aa)];                                                            \
      (w).y = (((b) & 1) == 0) ? wp[22 + ((b) >> 1)] : wp[36 + (((b) - 1) >> 1)];  \
      (w).z = (((b) & 1) == 0) ? wp[23 + ((b) >> 1)] : wp[37 + (((b) - 1) >> 1)]; }

#define WG(wv, buf, aa, B0)                 \
    { WLD1(wv[0], buf[0], aa, (B0) + 0);    \
      WLD1(wv[1], buf[1], aa, (B0) + 1);    \
      WLD1(wv[2], buf[2], aa, (B0) + 2);    \
      WLD1(wv[3], buf[3], aa, (B0) + 3);    \
      WLD1(wv[4], buf[4], aa, (B0) + 4);    \
      WLD1(wv[5], buf[5], aa, (B0) + 5);    \
      WLD1(wv[6], buf[6], aa, (B0) + 6);    \
      WLD1(wv[7], buf[7], aa, (B0) + 7); }

#define FMA1(pvv, w)                                                   \
    { uint W320, W100, W321, W101;                                     \
      MUL_WYLO(W320, (w).y, (w).x); MUL_WYLO(W100, (w).z, (w).x);      \
      MUL_WYHI(W321, (w).y, (w).x); MUL_WYHI(W101, (w).z, (w).x);      \
      FMA_LO(A32[0][0], (pvv).x, W320);                                \
      FMA_HI(A32[0][1], (pvv).x, W320);                                \
      FMA_HI(A32[0][2], (pvv).y, W320);                                \
      FMA_LO(A10[0][0], (pvv).x, W100);                                \
      FMA_HI(A10[0][1], (pvv).x, W100);                                \
      FMA_HI(A10[0][2], (pvv).y, W100);                                \
      FMA_LO(A32[1][0], (pvv).x, W321);                                \
      FMA_HI(A32[1][1], (pvv).x, W321);                                \
      FMA_HI(A32[1][2], (pvv).y, W321);                                \
      FMA_LO(A10[1][0], (pvv).x, W101);                                \
      FMA_HI(A10[1][1], (pvv).x, W101);                                \
      FMA_HI(A10[1][2], (pvv).y, W101); }

#define FMAG(buf, wv)          \
    { FMA1(buf[0], wv[0]);     \
      FMA1(buf[1], wv[1]);     \
      FMA1(buf[2], wv[2]);     \
      FMA1(buf[3], wv[3]);     \
      FMA1(buf[4], wv[4]);     \
      FMA1(buf[5], wv[5]);     \
      FMA1(buf[6], wv[6]);     \
      FMA1(buf[7], wv[7]); }

    // One source row: 3 groups of 8 taps, px prefetched 1-2 groups ahead,
    // weight loads batched (8 independent px->weight chains in flight).
#define ROW(aa)                            \
    { const int pxrow = pxbase + (aa) * LW;\
      uint2 p0[8], p1[8];                  \
      uint3 wv[8];                         \
      PXG(p0, 0);                          \
      PXG(p1, 8);                          \
      WG(wv, p0, (aa), 0);                 \
      FMAG(p0, wv);                        \
      PXG(p0, 16);                         \
      WG(wv, p1, (aa), 8);                 \
      FMAG(p1, wv);                        \
      WG(wv, p0, (aa), 16);                \
      FMAG(p0, wv); }

#define FLUSH()                                                        \
    { _Pragma("unroll")                                                \
      for (int r = 0; r < 2; ++r) {                                    \
          _Pragma("unroll")                                            \
          for (int c = 0; c < 3; ++c) {                                \
              float2 f3 = __half22float2(h2(A32[r][c]));               \
              float2 f1 = __half22float2(h2(A10[r][c]));               \
              mc[r][3][c] += f3.x; mc[r][2][c] += f3.y;                \
              mc[r][1][c] += f1.x; mc[r][0][c] += f1.y;                \
              A32[r][c] = 0; A10[r][c] = 0;                            \
          }                                                            \
      } }

    // 22 source rows, flush f16 partials (<=48 taps) every 2 rows
    #pragma unroll 1
    for (int ap = 0; ap < 11; ++ap) {
        ROW(2 * ap);
        ROW(2 * ap + 1);
        FLUSH();
    }

    // ---- store ----
    #pragma unroll
    for (int r = 0; r < 2; ++r) {
        int gy = Y0 + rowbase + r;
        #pragma unroll
        for (int m = 0; m < 4; ++m) {
            int gx = X0 + colbase + m;
            int o = (gy * IMG_W + gx) * 3;
            out[o + 0] = mc[r][m][0];
            out[o + 1] = mc[r][m][1];
            out[o + 2] = mc[r][m][2];
        }
    }
#undef ROW
#undef FLUSH
#undef PXG
#undef WG
#undef FMAG
#undef FMA1
#undef WLD1
#undef PIDX
}

extern "C" void kernel_launch(void* const* d_in, const int* in_sizes, int n_in,
                              void* d_out, int out_size, void* d_ws, size_t ws_size,
                              hipStream_t stream) {
    const float* img = (const float*)d_in[0];
    const int*   ks  = (const int*)d_in[1];
    float* out = (float*)d_out;

    dim3 grid(IMG_W / TILE, IMG_H / TILE);   // 32 x 32
    dim3 block(512);
    defocus_pipe_kernel<<<grid, block, 0, stream>>>(img, ks, out);
}